// Round 8
// baseline (241.683 us; speedup 1.0000x reference)
//
#include <hip/hip_runtime.h>

#define HPIX 256
#define WPIX 256
#define TSX 16
#define TSY 16
#define NTILE 256            // 16x16 tiles of 16x16 px
#define FCH 256
#define SEG_FLAT 16          // segments over all faces (fallback path)
#define NBUCK 4096           // minz counting-sort buckets over [1,2)
#define RSEG 8               // waves per quadrant block
#define RUN 8                // contiguous entries per wave per sweep
#define BIGF 1000000000.0f
#define EPSF 1e-8f
#define MARGIN 0.125f
#define HP_SLOP 0.0625f      // >= 4x the FP eval error bound (~0.015 w-units)
#define EPSZ 1e-4f           // early-exit slack >> depth/minz FP error (~2e-6)
#define SENT 0xFFFF0000u     // padding entry: bucket 0xFFFF, face 0
#define INIT_PACK 0xFFFFFFFFFFFFFFFFull

struct FaceRec {
  float x2, y2, a0, b0, a1, b1, inv, z0, z1, z2;
  float xmin, ymin, xmax, ymax;
};

// Compute the per-face record with EXACTLY the reference's op order (no FMA).
__device__ __forceinline__ FaceRec make_rec(const float* __restrict__ vb,
                                            const int* __restrict__ faces, int f) {
#pragma clang fp contract(off)
  FaceRec r;
  int i0 = faces[f * 3 + 0], i1 = faces[f * 3 + 1], i2 = faces[f * 3 + 2];
  float x0 = vb[i0 * 3 + 0], y0 = vb[i0 * 3 + 1], z0 = vb[i0 * 3 + 2];
  float x1 = vb[i1 * 3 + 0], y1 = vb[i1 * 3 + 1], z1 = vb[i1 * 3 + 2];
  float x2 = vb[i2 * 3 + 0], y2 = vb[i2 * 3 + 1], z2 = vb[i2 * 3 + 2];
  float px0 = x0 / z0, py0 = y0 / z0;
  float px1 = x1 / z1, py1 = y1 / z1;
  float px2 = x2 / z2, py2 = y2 / z2;
  float a0 = py1 - py2, b0 = px2 - px1;   // (y1-y2), (x2-x1)
  float a1 = py2 - py0, b1 = px0 - px2;   // (y2-y0), (x0-x2)
  float dy02 = py0 - py2;
  float denom = a0 * b1 + b0 * dy02;      // (y1-y2)*(x0-x2) + (x2-x1)*(y0-y2)
  bool nz = fabsf(denom) > EPSF;
  bool valid = nz && (z0 > 0.0f) && (z1 > 0.0f) && (z2 > 0.0f);
  r.x2 = px2; r.y2 = py2; r.a0 = a0; r.b0 = b0; r.a1 = a1; r.b1 = b1;
  r.inv = valid ? 1.0f / denom : 0.0f;
  r.z0 = z0; r.z1 = z1;
  r.z2 = valid ? z2 : -1.0f;              // invalid -> depth<0 -> fails depth>0
  if (valid) {
    r.xmin = fminf(px0, fminf(px1, px2)) - MARGIN;
    r.xmax = fmaxf(px0, fmaxf(px1, px2)) + MARGIN;
    r.ymin = fminf(py0, fminf(py1, py2)) - MARGIN;
    r.ymax = fmaxf(py0, fmaxf(py1, py2)) + MARGIN;
  } else {
    r.xmin = 2.0f * BIGF; r.xmax = -2.0f * BIGF;
    r.ymin = 2.0f * BIGF; r.ymax = -2.0f * BIGF;
  }
  return r;
}

// Same arithmetic as make_rec for the validity flag + minz (must match exactly).
__device__ __forceinline__ void classify(const float* __restrict__ vb,
                                         const int* __restrict__ faces, int f,
                                         bool& valid, float& minz) {
#pragma clang fp contract(off)
  int i0 = faces[f * 3 + 0], i1 = faces[f * 3 + 1], i2 = faces[f * 3 + 2];
  float x0 = vb[i0 * 3 + 0], y0 = vb[i0 * 3 + 1], z0 = vb[i0 * 3 + 2];
  float x1 = vb[i1 * 3 + 0], y1 = vb[i1 * 3 + 1], z1 = vb[i1 * 3 + 2];
  float x2 = vb[i2 * 3 + 0], y2 = vb[i2 * 3 + 1], z2 = vb[i2 * 3 + 2];
  float px0 = x0 / z0, py0 = y0 / z0;
  float px1 = x1 / z1, py1 = y1 / z1;
  float px2 = x2 / z2, py2 = y2 / z2;
  float a0 = py1 - py2, b0 = px2 - px1;
  float b1 = px0 - px2;
  float dy02 = py0 - py2;
  float denom = a0 * b1 + b0 * dy02;
  bool nz = fabsf(denom) > EPSF;
  valid = nz && (z0 > 0.0f) && (z1 > 0.0f) && (z2 > 0.0f);
  minz = fminf(z0, fminf(z1, z2));
}

__device__ __forceinline__ int bucket_of(bool valid, float minz) {
  if (!valid) return NBUCK - 1;
  float t = (minz - 1.0f) * (float)NBUCK;   // exact: Sterbenz + *2^12
  int b = (int)floorf(t);
  return b < 0 ? 0 : (b > NBUCK - 1 ? NBUCK - 1 : b);
}

// ---------- sorted path ----------
// prep: face-order records (coalesced) + minz-bucket histogram.
__global__ void prep_kernel(const float* __restrict__ verts,
                            const int* __restrict__ faces,
                            float4* __restrict__ recs,
                            unsigned int* __restrict__ hist,
                            int V, int F, int NIMG) {
  int idx = blockIdx.x * blockDim.x + threadIdx.x;
  if (idx >= NIMG * F) return;
  int n = idx / F, f = idx - n * F;
  const float* vb = verts + (size_t)n * V * 3;
  FaceRec r = make_rec(vb, faces, f);
  float4* o = recs + (size_t)idx * 4;
  o[0] = make_float4(r.x2, r.y2, r.a0, r.b0);
  o[1] = make_float4(r.a1, r.b1, r.inv, r.z0);
  o[2] = make_float4(r.z1, r.z2, 0.0f, 0.0f);
  o[3] = make_float4(r.xmin, r.ymin, r.xmax, r.ymax);
  if (hist) {
    bool valid; float minz;
    classify(vb, faces, f, valid, minz);
    atomicAdd(&hist[n * NBUCK + bucket_of(valid, minz)], 1u);
  }
}

__global__ __launch_bounds__(1024) void scan_kernel(unsigned int* __restrict__ hist) {
  __shared__ unsigned int s[1024];
  unsigned int* h = hist + (size_t)blockIdx.x * NBUCK;
  int t = threadIdx.x;
  unsigned int v0 = h[4 * t], v1 = h[4 * t + 1], v2 = h[4 * t + 2], v3 = h[4 * t + 3];
  unsigned int sum = v0 + v1 + v2 + v3;
  s[t] = sum;
  __syncthreads();
  for (int off = 1; off < 1024; off <<= 1) {
    unsigned int x = (t >= off) ? s[t - off] : 0u;
    __syncthreads();
    s[t] += x;
    __syncthreads();
  }
  unsigned int excl = s[t] - sum;
  h[4 * t] = excl;
  h[4 * t + 1] = excl + v0;
  h[4 * t + 2] = excl + v0 + v1;
  h[4 * t + 3] = excl + v0 + v1 + v2;
}

// perm[pos] = (bucket<<16) | face  in minz-sorted bucket order.
__global__ void perm_kernel(const float* __restrict__ verts,
                            const int* __restrict__ faces,
                            unsigned int* __restrict__ hist,
                            unsigned int* __restrict__ perm,
                            int V, int F, int NIMG) {
  int idx = blockIdx.x * blockDim.x + threadIdx.x;
  if (idx >= NIMG * F) return;
  int n = idx / F, f = idx - n * F;
  bool valid; float minz;
  classify(verts + (size_t)n * V * 3, faces, f, valid, minz);
  int b = bucket_of(valid, minz);
  unsigned int pos = atomicAdd(&hist[n * NBUCK + b], 1u);
  perm[(size_t)n * F + pos] = ((unsigned int)b << 16) | (unsigned int)f;
}

// Per (tile,image): scan sorted perm order, keep entries overlapping the tile
// (bbox + conservative corner half-plane), block-ordered compaction -> bin is
// ascending in bucket. Pads 64 sentinel entries after cnt.
__global__ __launch_bounds__(256) void bin_kernel(
    const float4* __restrict__ recs, const unsigned int* __restrict__ perm,
    unsigned int* __restrict__ cursors, unsigned int* __restrict__ bins,
    int F, int FP) {
#pragma clang fp contract(off)
  const int t = blockIdx.x, n = blockIdx.y;
  const int tlx = t & 15, tly = t >> 4;
  const float X0 = (float)(tlx * TSX), X1 = X0 + (float)(TSX - 1);
  const float Y0 = (float)(tly * TSY), Y1 = Y0 + (float)(TSY - 1);
  __shared__ unsigned int s_cnt[4];
  __shared__ unsigned int s_cur;
  const int tid = (int)threadIdx.x;
  const int lane = tid & 63, wid = tid >> 6;
  if (tid == 0) s_cur = 0u;
  __syncthreads();
  const float4* rb = recs + (size_t)n * F * 4;
  const unsigned int* pm = perm + (size_t)n * F;
  unsigned int* bin = bins + (size_t)(n * NTILE + t) * FP;
  for (int base = 0; base < F; base += 256) {
    int p = base + tid;
    unsigned int e = 0u;
    bool keep = false;
    if (p < F) {
      e = pm[p];
      int j = (int)(e & 0xFFFFu);
      float4 D = rb[j * 4 + 3];
      keep = (D.x <= X1) && (D.z >= X0) && (D.y <= Y1) && (D.w >= Y0);
      if (keep) {
        float4 A = rb[j * 4 + 0];
        float4 B = rb[j * 4 + 1];
        float inv = B.z;
        if (fabsf(inv) <= 1.0f) {
          float m0 = -3.0e38f, m1 = -3.0e38f, m2 = -3.0e38f;
#pragma unroll
          for (int c = 0; c < 4; ++c) {
            float ccx = (c & 1) ? X1 : X0;
            float ccy = (c & 2) ? Y1 : Y0;
            float bx = ccx - A.x, by = ccy - A.y;
            float w0 = (A.z * bx + A.w * by) * inv;
            float w1 = (B.x * bx + B.y * by) * inv;
            float w2 = 1.0f - w0 - w1;
            m0 = fmaxf(m0, w0); m1 = fmaxf(m1, w1); m2 = fmaxf(m2, w2);
          }
          keep = (m0 >= -HP_SLOP) && (m1 >= -HP_SLOP) && (m2 >= -HP_SLOP);
        }
      }
    }
    unsigned long long m = __ballot(keep);
    int cw = __popcll(m);
    if (lane == 0) s_cnt[wid] = (unsigned int)cw;
    __syncthreads();
    unsigned int woff = s_cur;
    for (int w = 0; w < wid; ++w) woff += s_cnt[w];
    unsigned int tot = s_cnt[0] + s_cnt[1] + s_cnt[2] + s_cnt[3];
    if (keep) {
      int off = __popcll(m & ((1ull << lane) - 1ull));
      bin[woff + (unsigned int)off] = e;
    }
    __syncthreads();             // all reads of s_cur/s_cnt done
    if (tid == 0) s_cur += tot;
  }
  __syncthreads();
  unsigned int cnt = s_cur;
  if (tid < 64) bin[cnt + (unsigned int)tid] = SENT;   // sentinel padding
  if (tid == 0) cursors[n * NTILE + t] = cnt;
}

// Epilogue: interpolate colors for the winning face, apply any-positive mask,
// write NCHW. Recomputes weights via make_rec -> bit-identical values.
__device__ __forceinline__ void emit_pixel(float* __restrict__ out,
    const float* __restrict__ vb, const float* __restrict__ colors,
    const int* __restrict__ faces, int n, int V, int C, int bestf,
    float cx, float cy, int row, int col) {
#pragma clang fp contract(off)
  float cv[8];
#pragma unroll
  for (int ch = 0; ch < 8; ++ch) cv[ch] = 0.0f;
  if (bestf >= 0) {
    int i0 = faces[bestf * 3 + 0], i1 = faces[bestf * 3 + 1], i2 = faces[bestf * 3 + 2];
    FaceRec r = make_rec(vb, faces, bestf);
    float bx = cx - r.x2, by = cy - r.y2;
    float w0 = (r.a0 * bx + r.b0 * by) * r.inv;
    float w1 = (r.a1 * bx + r.b1 * by) * r.inv;
    float w2 = 1.0f - w0 - w1;
    const float* c0 = colors + ((size_t)n * V + i0) * C;
    const float* c1 = colors + ((size_t)n * V + i1) * C;
    const float* c2 = colors + ((size_t)n * V + i2) * C;
    for (int ch = 0; ch < C && ch < 8; ++ch)
      cv[ch] = (w0 * c0[ch] + w1 * c1[ch]) + w2 * c2[ch];
  }
  bool anyp = false;
  for (int ch = 0; ch < C && ch < 8; ++ch) anyp = anyp || (cv[ch] > 0.0f);
  float m = anyp ? 1.0f : 0.0f;
  size_t base = (size_t)n * C * HPIX * WPIX + (size_t)row * WPIX + col;
  for (int ch = 0; ch < C && ch < 8; ++ch)
    out[base + (size_t)ch * HPIX * WPIX] = cv[ch] * m;
}

#define TESTJ(Ak, Bk, Zk, jk)                                                 \
  {                                                                           \
    float bx = cx - Ak.x, by = cy - Ak.y;                                     \
    float w0 = (Ak.z * bx + Ak.w * by) * Bk.z;                                \
    float w1 = (Bk.x * bx + Bk.y * by) * Bk.z;                                \
    float w2 = 1.0f - w0 - w1;                                                \
    float depth = (w0 * Bk.w + w1 * Zk.x) + w2 * Zk.y;                        \
    bool ok = (w0 >= 0.0f) && (w1 >= 0.0f) && (w2 >= 0.0f) && (depth > 0.0f); \
    if (ok) {                                                                 \
      unsigned long long p =                                                  \
          ((unsigned long long)__float_as_uint(depth) << 32) | (unsigned)(jk);\
      if (p < best) best = p;                                                 \
    }                                                                         \
  }

// 8 waves per 8x8 quadrant; wave w scans contiguous runs [w*8, w*8+8) stride
// 64 of the bucket-sorted bin. Exit key comes from the ENTRY ITSELF (no record
// load); per-entry bbox precheck (exact: outside padded bbox => test fails)
// gates the full test + A/B/Z loads. Shared per-pixel depth cut in LDS as
// before (hi-word read is always a real candidate depth; torn reads safe).
__global__ __launch_bounds__(512) void raster_sorted(
    const float4* __restrict__ recs, const unsigned int* __restrict__ bins,
    const unsigned int* __restrict__ cursors, const float* __restrict__ verts,
    const float* __restrict__ colors, const int* __restrict__ faces,
    float* __restrict__ out, int V, int F, int FP, int C) {
#pragma clang fp contract(off)
  __shared__ unsigned long long sdmin[64];
  const int bq = blockIdx.x;
  const int t = bq >> 2, quad = bq & 3;
  const int n = blockIdx.y;
  const int tlx = t & 15, tly = t >> 4;
  const int tid = (int)threadIdx.x;
  const int wave = tid >> 6, lane = tid & 63;
  const int tx = lane & 7, ty = lane >> 3;
  const int col = tlx * TSX + (quad & 1) * 8 + tx;
  const int row = tly * TSY + (quad >> 1) * 8 + ty;
  const float cx = (float)col, cy = (float)row;
  const float4* rb = recs + (size_t)n * F * 4;
  const unsigned int* bin = bins + (size_t)(n * NTILE + t) * FP;
  const int cnt = (int)cursors[n * NTILE + t];
  if (tid < 64) sdmin[tid] = INIT_PACK;
  __syncthreads();
  unsigned long long best = INIT_PACK;
  unsigned long long written = INIT_PACK;
  for (int base = wave * RUN; base < cnt; base += RSEG * RUN) {
    uint4 ea = *(const uint4*)(bin + base);        // padded: always safe
    uint4 eb = *(const uint4*)(bin + base + 4);
    // prefetch all 8 bboxes (independent scalar loads)
    int j0 = (int)(ea.x & 0xFFFFu), j1 = (int)(ea.y & 0xFFFFu);
    int j2 = (int)(ea.z & 0xFFFFu), j3 = (int)(ea.w & 0xFFFFu);
    int j4 = (int)(eb.x & 0xFFFFu), j5 = (int)(eb.y & 0xFFFFu);
    int j6 = (int)(eb.z & 0xFFFFu), j7 = (int)(eb.w & 0xFFFFu);
    float4 D0 = rb[j0 * 4 + 3], D1 = rb[j1 * 4 + 3];
    float4 D2 = rb[j2 * 4 + 3], D3 = rb[j3 * 4 + 3];
    float4 D4 = rb[j4 * 4 + 3], D5 = rb[j5 * 4 + 3];
    float4 D6 = rb[j6 * 4 + 3], D7 = rb[j7 * 4 + 3];
    // exit check on run's first (= smallest bucket) entry
    unsigned int b0 = ea.x >> 16;
    float key0 = (b0 == 0u) ? -3.0e38f
                            : 1.0f + (float)b0 * (1.0f / (float)NBUCK);
    unsigned long long sh = sdmin[lane];
    float dcut = __uint_as_float((unsigned int)(sh >> 32)); // NaN if INIT
    if (__all(key0 > dcut + EPSZ)) break;
#define PROC(ek, Dk, jk)                                                      \
    if (ek < SENT) {                                                          \
      bool inbox = (cx >= Dk.x) && (cx <= Dk.z) && (cy >= Dk.y) && (cy <= Dk.w); \
      if (__any(inbox)) {                                                     \
        float4 A = rb[jk * 4 + 0];                                            \
        float4 B = rb[jk * 4 + 1];                                            \
        float4 Z = rb[jk * 4 + 2];                                            \
        TESTJ(A, B, Z, jk);                                                   \
      }                                                                       \
    }
    PROC(ea.x, D0, j0) PROC(ea.y, D1, j1) PROC(ea.z, D2, j2) PROC(ea.w, D3, j3)
    PROC(eb.x, D4, j4) PROC(eb.y, D5, j5) PROC(eb.z, D6, j6) PROC(eb.w, D7, j7)
#undef PROC
    if (best < written) { atomicMin(&sdmin[lane], best); written = best; }
  }
  if (best < written) atomicMin(&sdmin[lane], best);
  __syncthreads();
  if (tid < 64) {
    unsigned long long b = sdmin[lane];
    int bestf = (b == INIT_PACK) ? -1 : (int)(unsigned int)(b & 0xFFFFFFFFull);
    emit_pixel(out, verts + (size_t)n * V * 3, colors, faces, n, V, C, bestf,
               cx, cy, row, col);
  }
}

// ---------- fallbacks (smaller ws or huge F) ----------
__global__ void init_kernel(unsigned long long* __restrict__ packed, int npix) {
  int i = blockIdx.x * blockDim.x + threadIdx.x;
  if (i < npix) packed[i] = INIT_PACK;
}

__device__ __forceinline__ void test_face(float4 A, float4 B, float4 Z, int f,
                                          float cx, float cy,
                                          unsigned long long& best) {
#pragma clang fp contract(off)
  float bx = cx - A.x, by = cy - A.y;
  float w0 = (A.z * bx + A.w * by) * B.z;
  float w1 = (B.x * bx + B.y * by) * B.z;
  float w2 = 1.0f - w0 - w1;
  float depth = (w0 * B.w + w1 * Z.x) + w2 * Z.y;
  bool ok = (w0 >= 0.0f) && (w1 >= 0.0f) && (w2 >= 0.0f) && (depth > 0.0f);
  if (ok) {
    unsigned long long p =
        ((unsigned long long)__float_as_uint(depth) << 32) | (unsigned int)f;
    best = p < best ? p : best;
  }
}

__global__ __launch_bounds__(256) void raster_seg(
    const float4* __restrict__ recs, unsigned long long* __restrict__ packed,
    int F) {
  const int tx = threadIdx.x, ty = threadIdx.y;
  const int n = blockIdx.z / SEG_FLAT, s = blockIdx.z % SEG_FLAT;
  const int col = blockIdx.x * TSX + tx, row = blockIdx.y * TSY + ty;
  const float cx = (float)col, cy = (float)row;
  const float tX0 = (float)(blockIdx.x * TSX), tX1 = tX0 + (float)(TSX - 1);
  const float tY0 = (float)(blockIdx.y * TSY), tY1 = tY0 + (float)(TSY - 1);
  const float4* rb = recs + (size_t)n * F * 4;
  unsigned long long best = INIT_PACK;
  for (int f = s; f < F; f += SEG_FLAT) {
    float4 bb = rb[f * 4 + 3];
    if (bb.x > tX1 || bb.z < tX0 || bb.y > tY1 || bb.w < tY0) continue;
    float4 A = rb[f * 4 + 0];
    float4 B = rb[f * 4 + 1];
    float4 Z = rb[f * 4 + 2];
    test_face(A, B, Z, f, cx, cy, best);
  }
  if (best != INIT_PACK)
    atomicMin(&packed[(size_t)n * (HPIX * WPIX) + row * WPIX + col], best);
}

__global__ __launch_bounds__(256) void resolve_kernel(
    const unsigned long long* __restrict__ packed,
    const float* __restrict__ verts, const float* __restrict__ colors,
    const int* __restrict__ faces, float* __restrict__ out,
    int V, int F, int C, int NIMG) {
  int i = blockIdx.x * blockDim.x + threadIdx.x;
  int total = NIMG * HPIX * WPIX;
  if (i >= total) return;
  int n = i / (HPIX * WPIX);
  int pix = i - n * (HPIX * WPIX);
  int row = pix >> 8, col = pix & 255;
  unsigned long long p = packed[i];
  int bestf = (p == INIT_PACK) ? -1 : (int)(unsigned int)(p & 0xFFFFFFFFull);
  emit_pixel(out, verts + (size_t)n * V * 3, colors, faces, n, V, C, bestf,
             (float)col, (float)row, row, col);
}

__global__ __launch_bounds__(256) void raster_l(const float* __restrict__ verts,
    const float* __restrict__ colors, const int* __restrict__ faces,
    float* __restrict__ out, int V, int F, int C) {
#pragma clang fp contract(off)
  __shared__ float4 sA[FCH], sB[FCH], sZ[FCH], sD[FCH];
  const int n = blockIdx.z;
  const int tx = threadIdx.x, ty = threadIdx.y;
  const int tid = ty * TSX + tx;
  const int col = blockIdx.x * TSX + tx;
  const int row = blockIdx.y * TSY + ty;
  const float cx = (float)col, cy = (float)row;
  const float tX0 = (float)(blockIdx.x * TSX), tX1 = tX0 + (float)(TSX - 1);
  const float tY0 = (float)(blockIdx.y * TSY), tY1 = tY0 + (float)(TSY - 1);
  const float* vb = verts + (size_t)n * V * 3;
  float bestd = BIGF;
  int bestf = -1;
  for (int base = 0; base < F; base += FCH) {
    int cnt = min(FCH, F - base);
    if (tid < cnt) {
      FaceRec r = make_rec(vb, faces, base + tid);
      sA[tid] = make_float4(r.x2, r.y2, r.a0, r.b0);
      sB[tid] = make_float4(r.a1, r.b1, r.inv, r.z0);
      sZ[tid] = make_float4(r.z1, r.z2, 0.0f, 0.0f);
      sD[tid] = make_float4(r.xmin, r.ymin, r.xmax, r.ymax);
    }
    __syncthreads();
    for (int j = 0; j < cnt; ++j) {
      float4 bb = sD[j];
      if (bb.x > tX1 || bb.z < tX0 || bb.y > tY1 || bb.w < tY0) continue;
      float4 A = sA[j];
      float4 B = sB[j];
      float4 Z = sZ[j];
      float bx = cx - A.x, by = cy - A.y;
      float w0 = (A.z * bx + A.w * by) * B.z;
      float w1 = (B.x * bx + B.y * by) * B.z;
      float w2 = 1.0f - w0 - w1;
      float depth = (w0 * B.w + w1 * Z.x) + w2 * Z.y;
      bool ok = (w0 >= 0.0f) && (w1 >= 0.0f) && (w2 >= 0.0f) && (depth > 0.0f);
      float d = ok ? depth : BIGF;
      if (d < bestd) { bestd = d; bestf = base + j; }
    }
    __syncthreads();
  }
  emit_pixel(out, vb, colors, faces, n, V, C, bestf, cx, cy, row, col);
}

extern "C" void kernel_launch(void* const* d_in, const int* in_sizes, int n_in,
                              void* d_out, int out_size, void* d_ws, size_t ws_size,
                              hipStream_t stream) {
  const float* verts = (const float*)d_in[0];
  const float* colors = (const float*)d_in[1];
  const int* faces = (const int*)d_in[2];
  float* out = (float*)d_out;
  long long s0 = in_sizes[0], s1 = in_sizes[1], s2 = in_sizes[2];
  int C = (int)((3LL * s1) / s0);
  if (C < 1) C = 1;
  int NC = out_size / (HPIX * WPIX);
  int N = NC / C;
  if (N < 1) N = 1;
  int V = (int)(s0 / (3LL * N));
  int F = (int)(s2 / 3);
  int FP = (F + 64 + 7) & ~7;              // padded bin stride (16B aligned)

  // sorted-path ws layout: recs | perm | hist | cursors | bins
  size_t offS = 0;
  size_t szS = (size_t)N * F * 4 * sizeof(float4);
  size_t offM = (offS + szS + 255) & ~(size_t)255;
  size_t szM = (size_t)N * F * sizeof(unsigned int);
  size_t offH = (offM + szM + 255) & ~(size_t)255;
  size_t szH = (size_t)N * NBUCK * sizeof(unsigned int);
  size_t offC2 = (offH + szH + 255) & ~(size_t)255;
  size_t szC2 = (size_t)N * NTILE * sizeof(unsigned int);
  size_t offB2 = (offC2 + szC2 + 255) & ~(size_t)255;
  size_t szB2 = (size_t)N * NTILE * (size_t)FP * sizeof(unsigned int);
  size_t need_sorted = offB2 + szB2;

  // fallback layout: recs | packed
  size_t szR = (size_t)N * F * 4 * sizeof(float4);
  size_t offP = (szR + 255) & ~(size_t)255;
  size_t szP = (size_t)N * HPIX * WPIX * sizeof(unsigned long long);

  dim3 block(TSX, TSY);
  char* ws = (char*)d_ws;
  int total = N * F;
  int npix = N * HPIX * WPIX;

  if (d_ws != nullptr && ws_size >= need_sorted && F < 65536) {
    float4* recs = (float4*)(ws + offS);
    unsigned int* perm = (unsigned int*)(ws + offM);
    unsigned int* hist = (unsigned int*)(ws + offH);
    unsigned int* cursors = (unsigned int*)(ws + offC2);
    unsigned int* bins = (unsigned int*)(ws + offB2);
    hipMemsetAsync(hist, 0, szH, stream);
    prep_kernel<<<(total + 255) / 256, 256, 0, stream>>>(verts, faces, recs,
                                                         hist, V, F, N);
    scan_kernel<<<N, 1024, 0, stream>>>(hist);
    perm_kernel<<<(total + 255) / 256, 256, 0, stream>>>(verts, faces, hist,
                                                         perm, V, F, N);
    bin_kernel<<<dim3(NTILE, N), 256, 0, stream>>>(recs, perm, cursors, bins,
                                                   F, FP);
    raster_sorted<<<dim3(NTILE * 4, N), 512, 0, stream>>>(recs, bins, cursors,
                                                          verts, colors, faces,
                                                          out, V, F, FP, C);
  } else if (d_ws != nullptr && ws_size >= offP + szP) {
    float4* recs = (float4*)ws;
    unsigned long long* packed = (unsigned long long*)(ws + offP);
    init_kernel<<<(npix + 255) / 256, 256, 0, stream>>>(packed, npix);
    prep_kernel<<<(total + 255) / 256, 256, 0, stream>>>(verts, faces, recs,
                                                         (unsigned int*)0,
                                                         V, F, N);
    raster_seg<<<dim3(16, 16, N * SEG_FLAT), block, 0, stream>>>(recs, packed, F);
    resolve_kernel<<<(npix + 255) / 256, 256, 0, stream>>>(packed, verts, colors,
                                                           faces, out, V, F, C, N);
  } else {
    raster_l<<<dim3(16, 16, N), block, 0, stream>>>(verts, colors, faces, out,
                                                    V, F, C);
  }
}